// Round 7
// baseline (225.810 us; speedup 1.0000x reference)
//
#include <hip/hip_runtime.h>
#include <stdint.h>

#define EMBED 1024
#define HEADS 16
#define HD 64
#define D3 3072
#define SEQ 2048
#define MROWS 4096

typedef __attribute__((ext_vector_type(8))) short short8;
typedef __attribute__((ext_vector_type(4))) float f32x4;
typedef __attribute__((ext_vector_type(16))) float f32x16;

static __device__ __forceinline__ ushort f2bf(float f) {
    uint32_t u = __builtin_bit_cast(uint32_t, f);
    uint32_t r = (u + 0x7fffu + ((u >> 16) & 1u)) >> 16;   // RNE
    return (ushort)r;
}

// async global->LDS, 16B per lane (wave-uniform dest base + lane*16).
static __device__ __forceinline__ void glds16(const void* g, void* l) {
    __builtin_amdgcn_global_load_lds(
        (const __attribute__((address_space(1))) uint32_t*)g,
        (__attribute__((address_space(3))) uint32_t*)(uintptr_t)l,
        16, 0, 0);
}

static __device__ __forceinline__ uint32_t cvt_pk_bf16(float lo, float hi) {
    uint32_t r;
    asm("v_cvt_pk_bf16_f32 %0, %1, %2" : "=v"(r) : "v"(lo), "v"(hi));
    return r;
}

// permlane32_swap via the INTRINSIC (compiler handles the VALU->permlane
// hazard wait-states that raw inline asm does not get - r6's failure).
// Semantics: a' = (a.lo32, b.lo32), b' = (a.hi32, b.hi32).
static __device__ __forceinline__ void pl32swap(uint32_t& a, uint32_t& b) {
    auto r = __builtin_amdgcn_permlane32_swap(a, b, false, false);
    uint32_t tmp[2];
    __builtin_memcpy(tmp, &r, 8);
    a = tmp[0];
    b = tmp[1];
}

// cross-half (lane ^ 32) reductions built on pl32swap
static __device__ __forceinline__ float xhalf_max(float x) {
    uint32_t a = __builtin_bit_cast(uint32_t, x), b = a;
    pl32swap(a, b);
    return fmaxf(__builtin_bit_cast(float, a), __builtin_bit_cast(float, b));
}
static __device__ __forceinline__ float xhalf_add(float x) {
    uint32_t a = __builtin_bit_cast(uint32_t, x), b = a;
    pl32swap(a, b);
    return __builtin_bit_cast(float, a) + __builtin_bit_cast(float, b);
}

// ---------------------------------------------------------------------------
__global__ __launch_bounds__(256) void cvt_f32_bf16(const float* __restrict__ in,
                                                    ushort* __restrict__ out, int n4) {
    int i = blockIdx.x * 256 + threadIdx.x;
    if (i < n4) {
        float4 v = reinterpret_cast<const float4*>(in)[i];
        ushort4 o = { f2bf(v.x), f2bf(v.y), f2bf(v.z), f2bf(v.w) };
        reinterpret_cast<ushort4*>(out)[i] = o;
    }
}

// ---------------------------------------------------------------------------
// C[M,N] = A[M,K]@W[N,K]^T + bias. 128x128 tile, BK=32, 4 waves (2x2),
// 16x16x32 bf16 MFMA, glds16 staging with pre-swizzled source. (unchanged)
// ---------------------------------------------------------------------------
template<int OUT_BF16>
__global__ __launch_bounds__(256) void gemm_bt_mfma(
    const ushort* __restrict__ A, const ushort* __restrict__ W,
    const float* __restrict__ bias, void* __restrict__ Cout,
    int M, int N, int K)
{
    __shared__ __align__(16) ushort As[128 * 32];
    __shared__ __align__(16) ushort Bs[128 * 32];

    const int t = threadIdx.x;
    const int lane = t & 63;
    const int w = t >> 6;
    const int wm = w >> 1, wn = w & 1;
    const int bm = blockIdx.y * 128, bn = blockIdx.x * 128;
    const int r16 = lane & 15, g = lane >> 4;

    f32x4 acc[4][4];
#pragma unroll
    for (int i = 0; i < 4; ++i)
#pragma unroll
        for (int j = 0; j < 4; ++j) acc[i][j] = (f32x4){0.f, 0.f, 0.f, 0.f};

    for (int k0 = 0; k0 < K; k0 += 32) {
#pragma unroll
        for (int p = 0; p < 2; ++p) {
            int c = t + p * 256;
            int row = c >> 2;
            int sg = (c & 3) ^ (row & 3);
            glds16(A + (size_t)(bm + row) * K + k0 + sg * 8, (char*)As + c * 16);
            glds16(W + (size_t)(bn + row) * K + k0 + sg * 8, (char*)Bs + c * 16);
        }
        __syncthreads();

        short8 af[4], bf[4];
#pragma unroll
        for (int mt = 0; mt < 4; ++mt) {
            int row = wm * 64 + mt * 16 + r16;
            int off = (g * 16) ^ ((row & 3) << 4);
            af[mt] = *reinterpret_cast<const short8*>((const char*)As + row * 64 + off);
        }
#pragma unroll
        for (int nt = 0; nt < 4; ++nt) {
            int row = wn * 64 + nt * 16 + r16;
            int off = (g * 16) ^ ((row & 3) << 4);
            bf[nt] = *reinterpret_cast<const short8*>((const char*)Bs + row * 64 + off);
        }
#pragma unroll
        for (int mt = 0; mt < 4; ++mt)
#pragma unroll
            for (int nt = 0; nt < 4; ++nt)
                acc[mt][nt] = __builtin_amdgcn_mfma_f32_16x16x32_bf16(
                    af[mt], bf[nt], acc[mt][nt], 0, 0, 0);
        __syncthreads();
    }

#pragma unroll
    for (int mt = 0; mt < 4; ++mt) {
#pragma unroll
        for (int nt = 0; nt < 4; ++nt) {
            int col = bn + wn * 64 + nt * 16 + r16;
            float bv = bias[col];
#pragma unroll
            for (int r = 0; r < 4; ++r) {
                size_t rowg = (size_t)(bm + wm * 64 + mt * 16 + g * 4 + r);
                float v = acc[mt][nt][r] + bv;
                if (OUT_BF16) ((ushort*)Cout)[rowg * N + col] = f2bf(v);
                else          ((float*)Cout)[rowg * N + col] = v;
            }
        }
    }
}

// ---------------------------------------------------------------------------
// Flash attention, 32x32x16 bf16 MFMA, swapped operands, QBLK=128 (4 waves x
// 32 q-rows), KVBLK=64. P stays ENTIRELY in registers:
//   S^T = mfma32(K, Q): lane(q=lane&31, hi=lane>>5) holds kc quads
//   {8M+4hi..+3}, M=4cb+(r>>2). PV B-frag for ks needs kc={16ks+8hi+0..7}:
//   pl32swap(pk[2ks][w], pk[2ks+1][w]) yields both frag halves for both
//   hi-lanes (own-quad + partner-quad). No P LDS traffic.
// Softmax exp2-domain with scale folded into fma; defer-max THR in raw
// domain (8/SC=44). dbuf K/V, 1 barrier/tile, setprio on MFMA clusters.
// LDS 32 KiB: K[2][64][64], Vt[2][64][64], rows 128B, 16B-slot XOR swizzle.
// ---------------------------------------------------------------------------
__global__ __launch_bounds__(256) void attn_mfma(
    const ushort* __restrict__ qkv, ushort* __restrict__ outb)
{
    __shared__ __align__(16) ushort lds[16384];   // 32 KiB

    const int t = threadIdx.x, lane = t & 63, w = t >> 6;
    const int qt = blockIdx.x, bh = blockIdx.y;
    const int b = bh >> 4, h = bh & 15;
    const int q31 = lane & 31, hi = lane >> 5;

    const ushort* Qb = qkv + (size_t)b * SEQ * D3 + h * HD;
    const ushort* Kb = Qb + EMBED;
    const ushort* Vb = Qb + 2 * EMBED;

    // Q fragments (B operand): col q=q31, k: d = 16ks + 8hi + j
    short8 qf[4];
    {
        const ushort* qrow = Qb + (size_t)(qt * 128 + w * 32 + q31) * D3 + 8 * hi;
#pragma unroll
        for (int ks = 0; ks < 4; ++ks)
            qf[ks] = *reinterpret_cast<const short8*>(qrow + ks * 16);
    }

    uint4 vv[2];
    auto stage_K = [&](int tile, ushort* dst) {
#pragma unroll
        for (int p = 0; p < 2; ++p) {
            int c = t + p * 256;
            int row = c >> 3;
            int sg = (c & 7) ^ (row & 7);
            glds16(Kb + (size_t)(tile * 64 + row) * D3 + sg * 8, (char*)dst + c * 16);
        }
    };
    auto load_V = [&](int tile) {
#pragma unroll
        for (int p = 0; p < 2; ++p) {
            int dseg = w * 2 + p;
            vv[p] = *reinterpret_cast<const uint4*>(
                Vb + (size_t)(tile * 64 + lane) * D3 + dseg * 8);
        }
    };
    auto write_V = [&](ushort* dst) {
#pragma unroll
        for (int p = 0; p < 2; ++p) {
            int dseg = w * 2 + p;
            ushort tmp[8];
            *reinterpret_cast<uint4*>(tmp) = vv[p];
#pragma unroll
            for (int j = 0; j < 8; ++j) {
                int d = dseg * 8 + j;
                int off = (lane * 2) ^ ((d & 7) << 4);
                *(ushort*)((char*)dst + d * 128 + off) = tmp[j];
            }
        }
    };

    f32x16 o[2];
#pragma unroll
    for (int db = 0; db < 2; ++db)
#pragma unroll
        for (int r = 0; r < 16; ++r) o[db][r] = 0.f;
    float m2 = -1e30f, lsum = 0.f;          // m2 tracked in RAW score domain

    const float SC = 0.18033688011112042f;  // 0.125 * log2(e)
    const float THR = 44.0f;                // ~8 / SC

    stage_K(0, lds);
    load_V(0);
    write_V(lds + 8192);
    __syncthreads();

    const int NT = SEQ / 64;
    for (int kt = 0; kt < NT; ++kt) {
        const int cur = kt & 1;
        ushort* Kc = lds + cur * 4096;
        ushort* Vc = lds + 8192 + cur * 4096;
        ushort* Kn = lds + (cur ^ 1) * 4096;
        ushort* Vn = lds + 8192 + (cur ^ 1) * 4096;
        const bool more = (kt + 1 < NT);

        if (more) { stage_K(kt + 1, Kn); load_V(kt + 1); }

        // QK^T: s[cb] = S^T block rows kc=32cb.., cols q (accumulate over ks)
        f32x16 s[2];
#pragma unroll
        for (int cb = 0; cb < 2; ++cb)
#pragma unroll
            for (int r = 0; r < 16; ++r) s[cb][r] = 0.f;

        __builtin_amdgcn_s_setprio(1);
#pragma unroll
        for (int cb = 0; cb < 2; ++cb) {
            int row = cb * 32 + q31;
            int swz = (row & 7) << 4;
#pragma unroll
            for (int ks = 0; ks < 4; ++ks) {
                int off = (32 * ks + 16 * hi) ^ swz;
                short8 kf = *reinterpret_cast<const short8*>((const char*)Kc + row * 128 + off);
                s[cb] = __builtin_amdgcn_mfma_f32_32x32x16_bf16(kf, qf[ks], s[cb], 0, 0, 0);
            }
        }
        __builtin_amdgcn_s_setprio(0);

        // row max (raw domain); partner lane^32 holds complementary kc
        float pmax = -1e30f;
#pragma unroll
        for (int cb = 0; cb < 2; ++cb)
#pragma unroll
            for (int r = 0; r < 16; r += 2)
                pmax = fmaxf(pmax, fmaxf(s[cb][r], s[cb][r + 1]));
        pmax = xhalf_max(pmax);

        if (!__all(pmax - m2 <= THR)) {       // defer-max rescale
            float mn = fmaxf(m2, pmax);
            float corr = exp2f((m2 - mn) * SC);
            lsum *= corr;
#pragma unroll
            for (int db = 0; db < 2; ++db)
#pragma unroll
                for (int r = 0; r < 16; ++r) o[db][r] *= corr;
            m2 = mn;
        }
        const float m2s = m2 * SC;

        // P = exp2(s*SC - m2s), packed to bf16 pairs entirely in registers.
        // pk[M][w]: M = 4cb + (r>>2) -> kc pair {8M+4hi+2w, +1}.
        uint32_t pk[8][2];
        float rs = 0.f;
#pragma unroll
        for (int cb = 0; cb < 2; ++cb)
#pragma unroll
            for (int rm = 0; rm < 4; ++rm)
#pragma unroll
                for (int wd = 0; wd < 2; ++wd) {
                    float p0 = exp2f(fmaf(s[cb][4 * rm + 2 * wd], SC, -m2s));
                    float p1 = exp2f(fmaf(s[cb][4 * rm + 2 * wd + 1], SC, -m2s));
                    rs += p0 + p1;
                    pk[4 * cb + rm][wd] = cvt_pk_bf16(p0, p1);
                }
        lsum += xhalf_add(rs);

        // Build PV B-frags: pl32swap(pk[2ks][w], pk[2ks+1][w]) -> words {w, w+2}
        short8 pB[4];
#pragma unroll
        for (int ks = 0; ks < 4; ++ks) {
            uint32_t a0 = pk[2 * ks][0], b0 = pk[2 * ks + 1][0];
            uint32_t a1 = pk[2 * ks][1], b1 = pk[2 * ks + 1][1];
            pl32swap(a0, b0);
            pl32swap(a1, b1);
            uint4 fr = { a0, a1, b0, b1 };
            pB[ks] = __builtin_bit_cast(short8, fr);
        }

        // PV: o[db] += mfma32(Vt rows d, P cols q)
        __builtin_amdgcn_s_setprio(1);
#pragma unroll
        for (int db = 0; db < 2; ++db) {
            int row = db * 32 + q31;
            int swz = (row & 7) << 4;
#pragma unroll
            for (int ks = 0; ks < 4; ++ks) {
                int off = (32 * ks + 16 * hi) ^ swz;
                short8 vf = *reinterpret_cast<const short8*>((const char*)Vc + row * 128 + off);
                o[db] = __builtin_amdgcn_mfma_f32_32x32x16_bf16(vf, pB[ks], o[db], 0, 0, 0);
            }
        }
        __builtin_amdgcn_s_setprio(0);

        if (more) write_V(Vn);
        __syncthreads();     // drains glds (vmcnt) + V ds_writes; buffers flip
    }

    // epilogue: lane owns q col q31; O^T rows d = (r&3)+8(r>>2)+4hi+32db
    const size_t orow = (size_t)b * SEQ + qt * 128 + w * 32 + q31;
    float inv = 1.f / lsum;
#pragma unroll
    for (int db = 0; db < 2; ++db) {
#pragma unroll
        for (int m = 0; m < 4; ++m) {
            int d0 = 32 * db + 8 * m + 4 * hi;
            ushort4 ov;
            ov.x = f2bf(o[db][4 * m + 0] * inv);
            ov.y = f2bf(o[db][4 * m + 1] * inv);
            ov.z = f2bf(o[db][4 * m + 2] * inv);
            ov.w = f2bf(o[db][4 * m + 3] * inv);
            *reinterpret_cast<ushort4*>(&outb[orow * EMBED + h * HD + d0]) = ov;
        }
    }
}

// ---------------------------------------------------------------------------
extern "C" void kernel_launch(void* const* d_in, const int* in_sizes, int n_in,
                              void* d_out, int out_size, void* d_ws, size_t ws_size,
                              hipStream_t stream)
{
    const float* x    = (const float*)d_in[0];
    const float* wqkv = (const float*)d_in[1];
    const float* bqkv = (const float*)d_in[2];
    const float* wo   = (const float*)d_in[3];
    const float* bo   = (const float*)d_in[4];
    float* out = (float*)d_out;

    ushort* xb    = (ushort*)d_ws;
    ushort* wqkvb = xb + (size_t)MROWS * EMBED;
    ushort* wob   = wqkvb + (size_t)D3 * EMBED;
    ushort* qkvb  = wob + (size_t)EMBED * EMBED;
    ushort* attnb = qkvb + (size_t)MROWS * D3;

    cvt_f32_bf16<<<4096, 256, 0, stream>>>(x,    xb,    MROWS * EMBED / 4);
    cvt_f32_bf16<<<3072, 256, 0, stream>>>(wqkv, wqkvb, D3 * EMBED / 4);
    cvt_f32_bf16<<<1024, 256, 0, stream>>>(wo,   wob,   EMBED * EMBED / 4);

    gemm_bt_mfma<1><<<dim3(D3 / 128, MROWS / 128), 256, 0, stream>>>(
        xb, wqkvb, bqkv, qkvb, MROWS, D3, EMBED);

    attn_mfma<<<dim3(SEQ / 128, 2 * HEADS), 256, 0, stream>>>(qkvb, attnb);

    gemm_bt_mfma<0><<<dim3(EMBED / 128, MROWS / 128), 256, 0, stream>>>(
        attnb, wob, bo, out, MROWS, EMBED, EMBED);
}

// Round 8
// 209.987 us; speedup vs baseline: 1.0754x; 1.0754x over previous
//
#include <hip/hip_runtime.h>
#include <stdint.h>

#define EMBED 1024
#define HEADS 16
#define HD 64
#define D3 3072
#define SEQ 2048
#define MROWS 4096

typedef __attribute__((ext_vector_type(8))) short short8;
typedef __attribute__((ext_vector_type(4))) float f32x4;
typedef __attribute__((ext_vector_type(16))) float f32x16;

static __device__ __forceinline__ ushort f2bf(float f) {
    uint32_t u = __builtin_bit_cast(uint32_t, f);
    uint32_t r = (u + 0x7fffu + ((u >> 16) & 1u)) >> 16;   // RNE
    return (ushort)r;
}

// raw v_exp_f32 (libm exp2f is a multi-instr libcall - r7's hidden VALU cost)
static __device__ __forceinline__ float fast_exp2(float x) {
#if __has_builtin(__builtin_amdgcn_exp2f)
    return __builtin_amdgcn_exp2f(x);
#else
    return __exp2f(x);
#endif
}

// async global->LDS, 16B per lane (wave-uniform dest base + lane*16).
static __device__ __forceinline__ void glds16(const void* g, void* l) {
    __builtin_amdgcn_global_load_lds(
        (const __attribute__((address_space(1))) uint32_t*)g,
        (__attribute__((address_space(3))) uint32_t*)(uintptr_t)l,
        16, 0, 0);
}

static __device__ __forceinline__ uint32_t cvt_pk_bf16(float lo, float hi) {
    uint32_t r;
    asm("v_cvt_pk_bf16_f32 %0, %1, %2" : "=v"(r) : "v"(lo), "v"(hi));
    return r;
}

// permlane32_swap via the INTRINSIC (compiler handles the VALU->permlane
// hazard wait-states that raw inline asm does not get - r6's failure).
// Semantics: a' = (a.lo32, b.lo32), b' = (a.hi32, b.hi32).
static __device__ __forceinline__ void pl32swap(uint32_t& a, uint32_t& b) {
    auto r = __builtin_amdgcn_permlane32_swap(a, b, false, false);
    uint32_t tmp[2];
    __builtin_memcpy(tmp, &r, 8);
    a = tmp[0];
    b = tmp[1];
}

// cross-half (lane ^ 32) reductions built on pl32swap
static __device__ __forceinline__ float xhalf_max(float x) {
    uint32_t a = __builtin_bit_cast(uint32_t, x), b = a;
    pl32swap(a, b);
    return fmaxf(__builtin_bit_cast(float, a), __builtin_bit_cast(float, b));
}
static __device__ __forceinline__ float xhalf_add(float x) {
    uint32_t a = __builtin_bit_cast(uint32_t, x), b = a;
    pl32swap(a, b);
    return __builtin_bit_cast(float, a) + __builtin_bit_cast(float, b);
}

// ---------------------------------------------------------------------------
__global__ __launch_bounds__(256) void cvt_f32_bf16(const float* __restrict__ in,
                                                    ushort* __restrict__ out, int n4) {
    int i = blockIdx.x * 256 + threadIdx.x;
    if (i < n4) {
        float4 v = reinterpret_cast<const float4*>(in)[i];
        ushort4 o = { f2bf(v.x), f2bf(v.y), f2bf(v.z), f2bf(v.w) };
        reinterpret_cast<ushort4*>(out)[i] = o;
    }
}

// ---------------------------------------------------------------------------
// C[M,N] = A[M,K]@W[N,K]^T + bias. 128x128 tile, BK=32, 4 waves (2x2),
// 16x16x32 bf16 MFMA, glds16 staging with pre-swizzled source. (unchanged)
// ---------------------------------------------------------------------------
template<int OUT_BF16>
__global__ __launch_bounds__(256) void gemm_bt_mfma(
    const ushort* __restrict__ A, const ushort* __restrict__ W,
    const float* __restrict__ bias, void* __restrict__ Cout,
    int M, int N, int K)
{
    __shared__ __align__(16) ushort As[128 * 32];
    __shared__ __align__(16) ushort Bs[128 * 32];

    const int t = threadIdx.x;
    const int lane = t & 63;
    const int w = t >> 6;
    const int wm = w >> 1, wn = w & 1;
    const int bm = blockIdx.y * 128, bn = blockIdx.x * 128;
    const int r16 = lane & 15, g = lane >> 4;

    f32x4 acc[4][4];
#pragma unroll
    for (int i = 0; i < 4; ++i)
#pragma unroll
        for (int j = 0; j < 4; ++j) acc[i][j] = (f32x4){0.f, 0.f, 0.f, 0.f};

    for (int k0 = 0; k0 < K; k0 += 32) {
#pragma unroll
        for (int p = 0; p < 2; ++p) {
            int c = t + p * 256;
            int row = c >> 2;
            int sg = (c & 3) ^ (row & 3);
            glds16(A + (size_t)(bm + row) * K + k0 + sg * 8, (char*)As + c * 16);
            glds16(W + (size_t)(bn + row) * K + k0 + sg * 8, (char*)Bs + c * 16);
        }
        __syncthreads();

        short8 af[4], bf[4];
#pragma unroll
        for (int mt = 0; mt < 4; ++mt) {
            int row = wm * 64 + mt * 16 + r16;
            int off = (g * 16) ^ ((row & 3) << 4);
            af[mt] = *reinterpret_cast<const short8*>((const char*)As + row * 64 + off);
        }
#pragma unroll
        for (int nt = 0; nt < 4; ++nt) {
            int row = wn * 64 + nt * 16 + r16;
            int off = (g * 16) ^ ((row & 3) << 4);
            bf[nt] = *reinterpret_cast<const short8*>((const char*)Bs + row * 64 + off);
        }
#pragma unroll
        for (int mt = 0; mt < 4; ++mt)
#pragma unroll
            for (int nt = 0; nt < 4; ++nt)
                acc[mt][nt] = __builtin_amdgcn_mfma_f32_16x16x32_bf16(
                    af[mt], bf[nt], acc[mt][nt], 0, 0, 0);
        __syncthreads();
    }

#pragma unroll
    for (int mt = 0; mt < 4; ++mt) {
#pragma unroll
        for (int nt = 0; nt < 4; ++nt) {
            int col = bn + wn * 64 + nt * 16 + r16;
            float bv = bias[col];
#pragma unroll
            for (int r = 0; r < 4; ++r) {
                size_t rowg = (size_t)(bm + wm * 64 + mt * 16 + g * 4 + r);
                float v = acc[mt][nt][r] + bv;
                if (OUT_BF16) ((ushort*)Cout)[rowg * N + col] = f2bf(v);
                else          ((float*)Cout)[rowg * N + col] = v;
            }
        }
    }
}

// ---------------------------------------------------------------------------
// Flash attention, 32x32x16 bf16 MFMA, swapped operands, QBLK=128 (4 waves x
// 32 q-rows), KVBLK=64. P stays ENTIRELY in registers:
//   S^T = mfma32(K, Q): lane(q=lane&31, hi=lane>>5) holds kc quads
//   {8M+4hi..+3}, M=4cb+(r>>2). PV B-frag for ks needs kc={16ks+8hi+0..7}:
//   pl32swap(pk[2ks][w], pk[2ks+1][w]) yields both frag halves for both
//   hi-lanes (own-quad + partner-quad). No P LDS traffic.
// Softmax exp2-domain via raw v_exp_f32; defer-max THR in raw domain.
// dbuf K/V, 1 barrier/tile, setprio on MFMA clusters.
// LDS 32 KiB: K[2][64][64], Vt[2][64][64], rows 128B, 16B-slot XOR swizzle.
// ---------------------------------------------------------------------------
__global__ __launch_bounds__(256) void attn_mfma(
    const ushort* __restrict__ qkv, ushort* __restrict__ outb)
{
    __shared__ __align__(16) ushort lds[16384];   // 32 KiB

    const int t = threadIdx.x, lane = t & 63, w = t >> 6;
    const int qt = blockIdx.x, bh = blockIdx.y;
    const int b = bh >> 4, h = bh & 15;
    const int q31 = lane & 31, hi = lane >> 5;

    const ushort* Qb = qkv + (size_t)b * SEQ * D3 + h * HD;
    const ushort* Kb = Qb + EMBED;
    const ushort* Vb = Qb + 2 * EMBED;

    // Q fragments (B operand): col q=q31, k: d = 16ks + 8hi + j
    short8 qf[4];
    {
        const ushort* qrow = Qb + (size_t)(qt * 128 + w * 32 + q31) * D3 + 8 * hi;
#pragma unroll
        for (int ks = 0; ks < 4; ++ks)
            qf[ks] = *reinterpret_cast<const short8*>(qrow + ks * 16);
    }

    uint4 vv[2];
    auto stage_K = [&](int tile, ushort* dst) {
#pragma unroll
        for (int p = 0; p < 2; ++p) {
            int c = t + p * 256;
            int row = c >> 3;
            int sg = (c & 7) ^ (row & 7);
            glds16(Kb + (size_t)(tile * 64 + row) * D3 + sg * 8, (char*)dst + c * 16);
        }
    };
    auto load_V = [&](int tile) {
#pragma unroll
        for (int p = 0; p < 2; ++p) {
            int dseg = w * 2 + p;
            vv[p] = *reinterpret_cast<const uint4*>(
                Vb + (size_t)(tile * 64 + lane) * D3 + dseg * 8);
        }
    };
    auto write_V = [&](ushort* dst) {
#pragma unroll
        for (int p = 0; p < 2; ++p) {
            int dseg = w * 2 + p;
            ushort tmp[8];
            *reinterpret_cast<uint4*>(tmp) = vv[p];
#pragma unroll
            for (int j = 0; j < 8; ++j) {
                int d = dseg * 8 + j;
                int off = (lane * 2) ^ ((d & 7) << 4);
                *(ushort*)((char*)dst + d * 128 + off) = tmp[j];
            }
        }
    };

    f32x16 o[2];
#pragma unroll
    for (int db = 0; db < 2; ++db)
#pragma unroll
        for (int r = 0; r < 16; ++r) o[db][r] = 0.f;
    float m2 = -1e30f, lsum = 0.f;          // m2 tracked in RAW score domain

    const float SC = 0.18033688011112042f;  // 0.125 * log2(e)
    const float THR = 44.0f;                // ~8 / SC
    const f32x16 kZero = {};                // hoisted zero C for first MFMA

    stage_K(0, lds);
    load_V(0);
    write_V(lds + 8192);
    __syncthreads();

    const int NT = SEQ / 64;
    for (int kt = 0; kt < NT; ++kt) {
        const int cur = kt & 1;
        ushort* Kc = lds + cur * 4096;
        ushort* Vc = lds + 8192 + cur * 4096;
        ushort* Kn = lds + (cur ^ 1) * 4096;
        ushort* Vn = lds + 8192 + (cur ^ 1) * 4096;
        const bool more = (kt + 1 < NT);

        if (more) { stage_K(kt + 1, Kn); load_V(kt + 1); }

        // QK^T: s[cb] = S^T block rows kc=32cb.., cols q (accumulate over ks)
        f32x16 s[2];
        __builtin_amdgcn_s_setprio(1);
#pragma unroll
        for (int cb = 0; cb < 2; ++cb) {
            int row = cb * 32 + q31;
            int swz = (row & 7) << 4;
#pragma unroll
            for (int ks = 0; ks < 4; ++ks) {
                int off = (32 * ks + 16 * hi) ^ swz;
                short8 kf = *reinterpret_cast<const short8*>((const char*)Kc + row * 128 + off);
                s[cb] = __builtin_amdgcn_mfma_f32_32x32x16_bf16(
                    kf, qf[ks], ks == 0 ? kZero : s[cb], 0, 0, 0);
            }
        }
        __builtin_amdgcn_s_setprio(0);

        // row max (raw domain); partner lane^32 holds complementary kc
        float pmax = -1e30f;
#pragma unroll
        for (int cb = 0; cb < 2; ++cb)
#pragma unroll
            for (int r = 0; r < 16; r += 2)
                pmax = fmaxf(pmax, fmaxf(s[cb][r], s[cb][r + 1]));
        pmax = xhalf_max(pmax);

        if (!__all(pmax - m2 <= THR)) {       // defer-max rescale
            float mn = fmaxf(m2, pmax);
            float corr = fast_exp2((m2 - mn) * SC);
            lsum *= corr;
#pragma unroll
            for (int db = 0; db < 2; ++db)
#pragma unroll
                for (int r = 0; r < 16; ++r) o[db][r] *= corr;
            m2 = mn;
        }
        const float m2s = m2 * SC;

        // P = exp2(s*SC - m2s), packed to bf16 pairs entirely in registers.
        // pk[M][w]: M = 4cb + (r>>2) -> kc pair {8M+4hi+2w, +1}.
        uint32_t pk[8][2];
        float rs = 0.f;
#pragma unroll
        for (int cb = 0; cb < 2; ++cb)
#pragma unroll
            for (int rm = 0; rm < 4; ++rm)
#pragma unroll
                for (int wd = 0; wd < 2; ++wd) {
                    float p0 = fast_exp2(fmaf(s[cb][4 * rm + 2 * wd], SC, -m2s));
                    float p1 = fast_exp2(fmaf(s[cb][4 * rm + 2 * wd + 1], SC, -m2s));
                    rs += p0 + p1;
                    pk[4 * cb + rm][wd] = cvt_pk_bf16(p0, p1);
                }
        lsum += xhalf_add(rs);

        // Build PV B-frags: pl32swap(pk[2ks][w], pk[2ks+1][w]) -> words {w, w+2}
        short8 pB[4];
#pragma unroll
        for (int ks = 0; ks < 4; ++ks) {
            uint32_t a0 = pk[2 * ks][0], b0 = pk[2 * ks + 1][0];
            uint32_t a1 = pk[2 * ks][1], b1 = pk[2 * ks + 1][1];
            pl32swap(a0, b0);
            pl32swap(a1, b1);
            uint4 fr = { a0, a1, b0, b1 };
            pB[ks] = __builtin_bit_cast(short8, fr);
        }

        // PV: o[db] += mfma32(Vt rows d, P cols q)
        __builtin_amdgcn_s_setprio(1);
#pragma unroll
        for (int db = 0; db < 2; ++db) {
            int row = db * 32 + q31;
            int swz = (row & 7) << 4;
#pragma unroll
            for (int ks = 0; ks < 4; ++ks) {
                int off = (32 * ks + 16 * hi) ^ swz;
                short8 vf = *reinterpret_cast<const short8*>((const char*)Vc + row * 128 + off);
                o[db] = __builtin_amdgcn_mfma_f32_32x32x16_bf16(vf, pB[ks], o[db], 0, 0, 0);
            }
        }
        __builtin_amdgcn_s_setprio(0);

        if (more) write_V(Vn);
        __syncthreads();     // drains glds (vmcnt) + V ds_writes; buffers flip
    }

    // epilogue: lane owns q col q31; O^T rows d = (r&3)+8(r>>2)+4hi+32db
    const size_t orow = (size_t)b * SEQ + qt * 128 + w * 32 + q31;
    float inv = 1.f / lsum;
#pragma unroll
    for (int db = 0; db < 2; ++db) {
#pragma unroll
        for (int m = 0; m < 4; ++m) {
            int d0 = 32 * db + 8 * m + 4 * hi;
            ushort4 ov;
            ov.x = f2bf(o[db][4 * m + 0] * inv);
            ov.y = f2bf(o[db][4 * m + 1] * inv);
            ov.z = f2bf(o[db][4 * m + 2] * inv);
            ov.w = f2bf(o[db][4 * m + 3] * inv);
            *reinterpret_cast<ushort4*>(&outb[orow * EMBED + h * HD + d0]) = ov;
        }
    }
}

// ---------------------------------------------------------------------------
extern "C" void kernel_launch(void* const* d_in, const int* in_sizes, int n_in,
                              void* d_out, int out_size, void* d_ws, size_t ws_size,
                              hipStream_t stream)
{
    const float* x    = (const float*)d_in[0];
    const float* wqkv = (const float*)d_in[1];
    const float* bqkv = (const float*)d_in[2];
    const float* wo   = (const float*)d_in[3];
    const float* bo   = (const float*)d_in[4];
    float* out = (float*)d_out;

    ushort* xb    = (ushort*)d_ws;
    ushort* wqkvb = xb + (size_t)MROWS * EMBED;
    ushort* wob   = wqkvb + (size_t)D3 * EMBED;
    ushort* qkvb  = wob + (size_t)EMBED * EMBED;
    ushort* attnb = qkvb + (size_t)MROWS * D3;

    cvt_f32_bf16<<<4096, 256, 0, stream>>>(x,    xb,    MROWS * EMBED / 4);
    cvt_f32_bf16<<<3072, 256, 0, stream>>>(wqkv, wqkvb, D3 * EMBED / 4);
    cvt_f32_bf16<<<1024, 256, 0, stream>>>(wo,   wob,   EMBED * EMBED / 4);

    gemm_bt_mfma<1><<<dim3(D3 / 128, MROWS / 128), 256, 0, stream>>>(
        xb, wqkvb, bqkv, qkvb, MROWS, D3, EMBED);

    attn_mfma<<<dim3(SEQ / 128, 2 * HEADS), 256, 0, stream>>>(qkvb, attnb);

    gemm_bt_mfma<0><<<dim3(EMBED / 128, MROWS / 128), 256, 0, stream>>>(
        attnb, wob, bo, out, MROWS, EMBED, EMBED);
}